// Round 10
// baseline (704.735 us; speedup 1.0000x reference)
//
#include <hip/hip_runtime.h>
#include <hip/hip_bf16.h>
#include <cstdint>
#include <cstddef>

#define BB    8
#define TT    1024
#define DD    1024
#define NHEAD 16
#define HDIM  64
#define FF    4096

typedef unsigned short u16;
typedef unsigned int   u32;
typedef short bf16x8 __attribute__((ext_vector_type(8)));
typedef float floatx4 __attribute__((ext_vector_type(4)));
typedef float floatx16 __attribute__((ext_vector_type(16)));
typedef __attribute__((address_space(1))) const u32 gu32;
typedef __attribute__((address_space(3))) u32 lu32;

#define ZERO16 {0.f,0.f,0.f,0.f,0.f,0.f,0.f,0.f,0.f,0.f,0.f,0.f,0.f,0.f,0.f,0.f}

__device__ __forceinline__ float b2f(u16 u) {
  union { u32 i; float f; } c; c.i = ((u32)u) << 16; return c.f;
}
__device__ __forceinline__ u16 f2b(float f) {
  union { float f; u32 i; } c; c.f = f;
  u32 x = c.i;
  u32 r = (x + 0x7fffu + ((x >> 16) & 1u)) >> 16;
  return (u16)r;
}

// ---------------- RMSNorm ----------------
__global__ __launch_bounds__(256) void rms_kernel(const float* __restrict__ x,
                                                  const float* __restrict__ g,
                                                  u16* __restrict__ xn) {
  int row = blockIdx.x;
  int tid = threadIdx.x;
  float4 v = ((const float4*)(x + (size_t)row * DD))[tid];
  float ss = v.x*v.x + v.y*v.y + v.z*v.z + v.w*v.w;
  for (int off = 32; off; off >>= 1) ss += __shfl_xor(ss, off);
  __shared__ float red[4];
  if ((tid & 63) == 0) red[tid >> 6] = ss;
  __syncthreads();
  float tot = red[0] + red[1] + red[2] + red[3];
  float inv = rsqrtf(tot * (1.0f / DD) + 1e-6f);
  float4 gv = ((const float4*)g)[tid];
  ushort4 o;
  o.x = f2b(v.x * inv * gv.x);
  o.y = f2b(v.y * inv * gv.y);
  o.z = f2b(v.z * inv * gv.z);
  o.w = f2b(v.w * inv * gv.w);
  ((ushort4*)(xn + (size_t)row * DD))[tid] = o;
}

// ---------------- LayerNorm (fp32 in, bf16 out) ----------------
__global__ __launch_bounds__(256) void ln_kernel(const float* __restrict__ a,
                                                 const float* __restrict__ g,
                                                 const float* __restrict__ be,
                                                 u16* __restrict__ o) {
  int row = blockIdx.x;
  int tid = threadIdx.x;
  float4 v = ((const float4*)(a + (size_t)row * DD))[tid];
  float s1 = v.x + v.y + v.z + v.w;
  float s2 = v.x*v.x + v.y*v.y + v.z*v.z + v.w*v.w;
  for (int off = 32; off; off >>= 1) {
    s1 += __shfl_xor(s1, off);
    s2 += __shfl_xor(s2, off);
  }
  __shared__ float r1[4], r2[4];
  if ((tid & 63) == 0) { r1[tid >> 6] = s1; r2[tid >> 6] = s2; }
  __syncthreads();
  float S1 = r1[0] + r1[1] + r1[2] + r1[3];
  float S2 = r2[0] + r2[1] + r2[2] + r2[3];
  float mean = S1 * (1.0f / DD);
  float var  = S2 * (1.0f / DD) - mean * mean;
  float inv  = rsqrtf(var + 1e-5f);
  float4 gv = ((const float4*)g)[tid];
  float4 bv = ((const float4*)be)[tid];
  ushort4 out;
  out.x = f2b((v.x - mean) * inv * gv.x + bv.x);
  out.y = f2b((v.y - mean) * inv * gv.y + bv.y);
  out.z = f2b((v.z - mean) * inv * gv.z + bv.z);
  out.w = f2b((v.w - mean) * inv * gv.w + bv.w);
  ((ushort4*)(o + (size_t)row * DD))[tid] = out;
}

// ------------- per-column bias+scale arrays for fused QKV -------------
// NOTE: q-scale carries an EXTRA log2(e) factor: softmax is computed in
// exp2 domain inside attn_mfma (exp(s) == exp2(s*log2e)).
__global__ void prep_kernel(const float* __restrict__ bq, const float* __restrict__ bk,
                            const float* __restrict__ bv, const float* __restrict__ pds,
                            float* __restrict__ bqkv, float* __restrict__ qsall) {
  int j = blockIdx.x * 1024 + threadIdx.x;  // 3 blocks x 1024
  float b = (j < 1024) ? bq[j] : (j < 2048) ? bk[j - 1024] : bv[j - 2048];
  bqkv[j] = b;
  float s = 1.f;
  if (j < 1024) {
    float p = pds[j & 63];
    float sp = (p > 0.f) ? (p + log1pf(__expf(-p))) : log1pf(__expf(p));
    s = 0.26017112252f * sp;  // (LOG2E^2)/sqrt(64) * softplus  (exp2-domain)
  }
  qsall[j] = s;
}

// ------------- weight transpose+convert: in[R][C] fp32 -> out[C][R] bf16 -------
__global__ __launch_bounds__(256) void transpose_conv(const float* __restrict__ in,
                                                      u16* __restrict__ out,
                                                      int R, int C) {
  __shared__ float t[32][33];
  int bx = blockIdx.x * 32, by = blockIdx.y * 32;
  int tx = threadIdx.x & 31, ty = threadIdx.x >> 5;  // 32 x 8
#pragma unroll
  for (int i = 0; i < 32; i += 8)
    t[ty + i][tx] = in[(size_t)(by + ty + i) * C + bx + tx];
  __syncthreads();
#pragma unroll
  for (int i = 0; i < 32; i += 8)
    out[(size_t)(bx + ty + i) * R + by + tx] = f2b(t[tx][ty + i]);
}

// ------------- elementwise fp32 -> bf16 convert -------------
__global__ __launch_bounds__(256) void conv_bf16(const float* __restrict__ in,
                                                 u16* __restrict__ out) {
  int i = blockIdx.x * 256 + threadIdx.x;
  float4 v = ((const float4*)in)[i];
  ushort4 o = { f2b(v.x), f2b(v.y), f2b(v.z), f2b(v.w) };
  ((ushort4*)out)[i] = o;
}

// ------------- V transpose per (b,n): vdst[bn][h][t] = vsrc[b*T+t][n*64+h] ----
__global__ __launch_bounds__(256) void vtrans_kernel(const u16* __restrict__ vsrc,
                                                     u16* __restrict__ vdst) {
  __shared__ u16 tile[64][65];
  int bn = blockIdx.y; int b = bn >> 4, n = bn & 15;
  int t0 = blockIdx.x * 64;
  int tid = threadIdx.x;
  int rr = tid >> 4;
  int c4 = (tid & 15) * 4;
#pragma unroll
  for (int i = 0; i < 4; i++) {
    int r = i * 16 + rr;
    ushort4 d = *(const ushort4*)(vsrc + ((size_t)(b * TT + t0 + r)) * DD + n * HDIM + c4);
    tile[r][c4 + 0] = d.x; tile[r][c4 + 1] = d.y;
    tile[r][c4 + 2] = d.z; tile[r][c4 + 3] = d.w;
  }
  __syncthreads();
#pragma unroll
  for (int i = 0; i < 4; i++) {
    int h = i * 16 + rr;
    ushort4 d;
    d.x = tile[c4 + 0][h]; d.y = tile[c4 + 1][h];
    d.z = tile[c4 + 2][h]; d.w = tile[c4 + 3][h];
    *(ushort4*)(vdst + ((size_t)bn * HDIM + h) * TT + t0 + c4) = d;
  }
}

// ---------------- MFMA GEMM wide: 128x256 tile, BK=64, 2-barrier ------------
// Same sync structure as the proven 128^2 BK=64 kernel (parameter change only).
// 256 threads = 4 waves, wave-tile 64x128: per K=32 each wave does 12 ds_read
// for 32 MFMAs (vs 8:16 at 128^2) -> MFMA-bound ratio. LDS 48 KiB -> 3/CU by
// LDS; VGPR ~acc128+frags -> ~2 blocks/CU. bf-frags loaded in two halves to
// cut live range. Requires M%128==0, N%256==0, K%64==0, grid %8==0.
template <typename OUT_T>
__global__ __launch_bounds__(256) void mfma_gemm_wide(
    const u16* __restrict__ A, const u16* __restrict__ Bt,
    const float* __restrict__ bias, const float* __restrict__ accsrc,
    const float* __restrict__ scale, OUT_T* __restrict__ C,
    int lda, int ldb, int K, int relu, int ldc, size_t regstride) {
  __shared__ u16 As[2][128 * 32] __attribute__((aligned(16)));
  __shared__ u16 Bs[2][256 * 32] __attribute__((aligned(16)));
  int tid = threadIdx.x;
  int lane = tid & 63;
  int wave = tid >> 6;
  int nbx = gridDim.x;
  int nwg = nbx * gridDim.y;
  int bid = blockIdx.y * nbx + blockIdx.x;
  int wid = (bid & 7) * (nwg >> 3) + (bid >> 3);
  int row0 = (wid / nbx) * 128, col0 = (wid % nbx) * 256;

  int sr = tid >> 2;
  int sk = (tid & 3) << 3;
  const u16* ag = A  + (size_t)(row0 + sr) * lda + sk;
  const u16* bg = Bt + (size_t)(col0 + sr) * ldb + sk;
  size_t rstep = (size_t)64;   // row step in rows

  int wr = (wave >> 1) * 64;   // wave M-offset: 0 / 64
  int wc = (wave & 1) * 128;   // wave N-offset: 0 / 128
  int fr = lane & 15;
  int fq = lane >> 4;

  floatx4 acc[4][8];
#pragma unroll
  for (int mi = 0; mi < 4; mi++)
#pragma unroll
    for (int ni = 0; ni < 8; ni++)
      acc[mi][ni] = (floatx4){0.f, 0.f, 0.f, 0.f};

  for (int k0 = 0; k0 < K; k0 += 64) {
#pragma unroll
    for (int kk = 0; kk < 2; kk++) {
      const u16* a_ = ag + kk * 32;
      const u16* b_ = bg + kk * 32;
      u16* asl = As[kk] + tid * 8;
      u16* bsl = Bs[kk] + tid * 8;
      __builtin_amdgcn_global_load_lds((gu32*)a_,                  (lu32*)asl,          16, 0, 0);
      __builtin_amdgcn_global_load_lds((gu32*)(a_ + rstep * lda),  (lu32*)(asl + 2048), 16, 0, 0);
      __builtin_amdgcn_global_load_lds((gu32*)b_,                  (lu32*)bsl,          16, 0, 0);
      __builtin_amdgcn_global_load_lds((gu32*)(b_ + rstep * ldb),      (lu32*)(bsl + 2048), 16, 0, 0);
      __builtin_amdgcn_global_load_lds((gu32*)(b_ + 2 * rstep * ldb),  (lu32*)(bsl + 4096), 16, 0, 0);
      __builtin_amdgcn_global_load_lds((gu32*)(b_ + 3 * rstep * ldb),  (lu32*)(bsl + 6144), 16, 0, 0);
    }
    __syncthreads();
#pragma unroll
    for (int kk = 0; kk < 2; kk++) {
      const bf16x8* afp = (const bf16x8*)(As[kk] + (size_t)(wr + fr) * 32 + fq * 8);
      const bf16x8* bfp = (const bf16x8*)(Bs[kk] + (size_t)(wc + fr) * 32 + fq * 8);
      bf16x8 af[4], bf[4];
#pragma unroll
      for (int mi = 0; mi < 4; mi++) af[mi] = afp[mi * 64];
#pragma unroll
      for (int ni = 0; ni < 4; ni++) bf[ni] = bfp[ni * 64];
#pragma unroll
      for (int mi = 0; mi < 4; mi++)
#pragma unroll
        for (int ni = 0; ni < 4; ni++)
          acc[mi][ni] = __builtin_amdgcn_mfma_f32_16x16x32_bf16(
              af[mi], bf[ni], acc[mi][ni], 0, 0, 0);
#pragma unroll
      for (int ni = 0; ni < 4; ni++) bf[ni] = bfp[(ni + 4) * 64];
#pragma unroll
      for (int mi = 0; mi < 4; mi++)
#pragma unroll
        for (int ni = 0; ni < 4; ni++)
          acc[mi][ni + 4] = __builtin_amdgcn_mfma_f32_16x16x32_bf16(
              af[mi], bf[ni], acc[mi][ni + 4], 0, 0, 0);
    }
    __syncthreads();
    ag += 64; bg += 64;
  }

#pragma unroll
  for (int mi = 0; mi < 4; mi++) {
    int rbase = row0 + wr + mi * 16 + fq * 4;
#pragma unroll
    for (int ni = 0; ni < 8; ni++) {
      int col = col0 + wc + ni * 16 + fr;
      float bcol = bias ? bias[col] : 0.f;
      float scl  = scale ? scale[col] : 1.f;
      size_t cbase = regstride ? ((size_t)(col >> 10) * regstride + (col & 1023))
                               : (size_t)col;
#pragma unroll
      for (int reg = 0; reg < 4; reg++) {
        int r = rbase + reg;
        float v = (acc[mi][ni][reg] + bcol) * scl;
        if (relu)   v = fmaxf(v, 0.f);
        if (accsrc) v += accsrc[(size_t)r * ldc + col];
        if constexpr (sizeof(OUT_T) == 2) ((u16*)C)[cbase + (size_t)r * ldc] = f2b(v);
        else                              ((float*)C)[cbase + (size_t)r * ldc] = v;
      }
    }
  }
}

// ---------------- MFMA GEMM (128^2, BK=64 — round-7 proven version) ----------
template <typename OUT_T>
__global__ __launch_bounds__(256) void mfma_gemm(
    const u16* __restrict__ A, const u16* __restrict__ Bt,
    const float* __restrict__ bias, const float* __restrict__ accsrc,
    const float* __restrict__ scale, OUT_T* __restrict__ C,
    int lda, int ldb, int K, int relu, int ldc, size_t regstride) {
  __shared__ u16 As[2][128 * 32] __attribute__((aligned(16)));
  __shared__ u16 Bs[2][128 * 32] __attribute__((aligned(16)));
  int tid = threadIdx.x;
  int lane = tid & 63;
  int wave = tid >> 6;
  int nbx = gridDim.x;
  int nwg = nbx * gridDim.y;
  int bid = blockIdx.y * nbx + blockIdx.x;
  int wid = (bid & 7) * (nwg >> 3) + (bid >> 3);
  int row0 = (wid / nbx) * 128, col0 = (wid % nbx) * 128;

  int sr = tid >> 2;
  int sk = (tid & 3) << 3;
  const u16* ag = A  + (size_t)(row0 + sr) * lda + sk;
  const u16* bg = Bt + (size_t)(col0 + sr) * ldb + sk;
  size_t rstepA = (size_t)64 * lda;
  size_t rstepB = (size_t)64 * ldb;

  int wr = (wave >> 1) * 64;
  int wc = (wave & 1) * 64;
  int fr = lane & 15;
  int fq = lane >> 4;

  floatx4 acc[4][4];
#pragma unroll
  for (int mi = 0; mi < 4; mi++)
#pragma unroll
    for (int ni = 0; ni < 4; ni++)
      acc[mi][ni] = (floatx4){0.f, 0.f, 0.f, 0.f};

  for (int k0 = 0; k0 < K; k0 += 64) {
#pragma unroll
    for (int kk = 0; kk < 2; kk++) {
      const u16* a_ = ag + kk * 32;
      const u16* b_ = bg + kk * 32;
      u16* asl = As[kk] + tid * 8;
      u16* bsl = Bs[kk] + tid * 8;
      __builtin_amdgcn_global_load_lds((gu32*)a_,            (lu32*)asl,          16, 0, 0);
      __builtin_amdgcn_global_load_lds((gu32*)(a_ + rstepA), (lu32*)(asl + 2048), 16, 0, 0);
      __builtin_amdgcn_global_load_lds((gu32*)b_,            (lu32*)bsl,          16, 0, 0);
      __builtin_amdgcn_global_load_lds((gu32*)(b_ + rstepB), (lu32*)(bsl + 2048), 16, 0, 0);
    }
    __syncthreads();
#pragma unroll
    for (int kk = 0; kk < 2; kk++) {
      const bf16x8* afp = (const bf16x8*)(As[kk] + (size_t)(wr + fr) * 32 + fq * 8);
      const bf16x8* bfp = (const bf16x8*)(Bs[kk] + (size_t)(wc + fr) * 32 + fq * 8);
      bf16x8 af[4], bf[4];
#pragma unroll
      for (int mi = 0; mi < 4; mi++) af[mi] = afp[mi * 64];
#pragma unroll
      for (int ni = 0; ni < 4; ni++) bf[ni] = bfp[ni * 64];
#pragma unroll
      for (int mi = 0; mi < 4; mi++)
#pragma unroll
        for (int ni = 0; ni < 4; ni++)
          acc[mi][ni] = __builtin_amdgcn_mfma_f32_16x16x32_bf16(
              af[mi], bf[ni], acc[mi][ni], 0, 0, 0);
    }
    __syncthreads();
    ag += 64; bg += 64;
  }

#pragma unroll
  for (int mi = 0; mi < 4; mi++) {
    int rbase = row0 + wr + mi * 16 + fq * 4;
#pragma unroll
    for (int ni = 0; ni < 4; ni++) {
      int col = col0 + wc + ni * 16 + fr;
      float bcol = bias ? bias[col] : 0.f;
      float scl  = scale ? scale[col] : 1.f;
      size_t cbase = regstride ? ((size_t)(col >> 10) * regstride + (col & 1023))
                               : (size_t)col;
#pragma unroll
      for (int reg = 0; reg < 4; reg++) {
        int r = rbase + reg;
        float v = (acc[mi][ni][reg] + bcol) * scl;
        if (relu)   v = fmaxf(v, 0.f);
        if (accsrc) v += accsrc[(size_t)r * ldc + col];
        if constexpr (sizeof(OUT_T) == 2) ((u16*)C)[cbase + (size_t)r * ldc] = f2b(v);
        else                              ((float*)C)[cbase + (size_t)r * ldc] = v;
      }
    }
  }
}

// ---------------- MFMA flash attention (balanced q-tile pairs) ----------------
__global__ __launch_bounds__(256) void attn_mfma(
    const u16* __restrict__ q, const u16* __restrict__ k,
    const u16* __restrict__ vT, const float* __restrict__ padc,
    u16* __restrict__ ao) {
  int nwg = gridDim.x * gridDim.y;        // 4 * G*16, %8 == 0
  int bid = blockIdx.y * gridDim.x + blockIdx.x;
  int wid = (bid & 7) * (nwg >> 3) + (bid >> 3);
  int p  = wid & 3;
  int bn = wid >> 2;
  int b = bn >> 4, n = bn & 15;
  int tid = threadIdx.x;
  int w = tid >> 6, lane = tid & 63;
  int cl = lane & 31, hf = lane >> 5;
  __shared__ u16 Qs[128 * 64] __attribute__((aligned(16)));
  __shared__ u16 Ks[64 * 64]  __attribute__((aligned(16)));
  __shared__ u16 Vts[64 * 64] __attribute__((aligned(16)));
  __shared__ float padl[64];

  for (int half = 0; half < 2; half++) {
    int qt = half ? (7 - p) : p;
    int q0g = qt * 128;

#pragma unroll
    for (int it = 0; it < 4; it++) {
      int cid = it * 256 + tid; int r = cid >> 3, cc = cid & 7;
      uint4 d = *(const uint4*)(q + ((size_t)(b * TT + q0g + r)) * DD + n * HDIM + cc * 8);
      ((uint4*)Qs)[r * 8 + (cc ^ (r & 7))] = d;
    }
    __syncthreads();
    bf16x8 qf[4];
    int qrow = 32 * w + cl;
#pragma unroll
    for (int kc = 0; kc < 4; kc++)
      qf[kc] = ((const bf16x8*)Qs)[qrow * 8 + ((2 * kc + hf) ^ (cl & 7))];

    int tq = q0g + qrow;
    float prow = padc[b * TT + tq];
    bool prow_ok = (prow != 0.f);
    floatx16 o0 = ZERO16, o1 = ZERO16;
    float m_i = -INFINITY, l_i = 0.f;

    int jend = q0g + 128;
    for (int j0 = 0; j0 < jend; j0 += 64) {
#pragma unroll
      for (int it = 0; it < 2; it++) {
        int cid = it * 256 + tid; int r = cid >> 3, cc = cid & 7;
        uint4 dk = *(const uint4*)(k + ((size_t)(b * TT + j0 + r)) * DD + n * HDIM + cc * 8);
        ((uint4*)Ks)[r * 8 + (cc ^ (r & 7))] = dk;
        uint4 dv = *(const uint4*)(vT + ((size_t)(bn * HDIM + r)) * TT + j0 + cc * 8);
        ((uint4*)Vts)[r * 8 + (cc ^ (r & 7))] = dv;
      }
      if (tid < 64) padl[tid] = padc[b * TT + j0 + tid];
      __syncthreads();

      floatx16 s0 = ZERO16, s1 = ZERO16;
#pragma unroll
      for (int kc = 0; kc < 4; kc++) {
        bf16x8 ka0 = ((const bf16x8*)Ks)[cl * 8 + ((2 * kc + hf) ^ (cl & 7))];
        bf16x8 ka1 = ((const bf16x8*)Ks)[(32 + cl) * 8 + ((2 * kc + hf) ^ (cl & 7))];
        s0 = __builtin_amdgcn_mfma_f32_32x32x16_bf16(ka0, qf[kc], s0, 0, 0, 0);
        s1 = __builtin_amdgcn_mfma_f32_32x32x16_bf16(ka1, qf[kc], s1, 0, 0, 0);
      }

      float pl = padl[lane];
      bool fullt = (j0 + 63 <= q0g + 32 * w) && __all(pl != 0.f) && __all((int)prow_ok);
      float mloc = -INFINITY;
      if (fullt) {
#pragma unroll
        for (int i = 0; i < 16; i++)
          mloc = fmaxf(mloc, fmaxf(s0[i], s1[i]));
      } else {
#pragma unroll
        for (int q2 = 0; q2 < 2; q2++) {
#pragma unroll
          for (int rg = 0; rg < 4; rg++) {
            float4 pv = *(const float4*)&padl[q2 * 32 + rg * 8 + 4 * hf];
            int kb = j0 + q2 * 32 + rg * 8 + 4 * hf;
#pragma unroll
            for (int j = 0; j < 4; j++) {
              int idx = rg * 4 + j;
              float sval = q2 ? s1[idx] : s0[idx];
              float pvj = (j == 0) ? pv.x : (j == 1) ? pv.y : (j == 2) ? pv.z : pv.w;
              bool ok = prow_ok && (kb + j <= tq) && (pvj != 0.f);
              sval = ok ? sval : -1e9f;
              if (q2) s1[idx] = sval; else s0[idx] = sval;
              mloc = fmaxf(mloc, sval);
            }
          }
        }
      }
      float mtile = fmaxf(mloc, __shfl_xor(mloc, 32));
      float mnew = fmaxf(m_i, mtile);
      float alpha = exp2f(m_i - mnew);
      m_i = mnew;
      float ls = 0.f;
#pragma unroll
      for (int i = 0; i < 16; i++) {
        float p0 = exp2f(s0[i] - mnew); s0[i] = p0; ls += p0;
        float p1 = exp2f(s1[i] - mnew); s1[i] = p1; ls += p1;
      }
      ls += __shfl_xor(ls, 32);
      l_i = l_i * alpha + ls;
      o0 *= alpha; o1 *= alpha;

      u32 pk[8][2];
#pragma unroll
      for (int q2 = 0; q2 < 2; q2++)
#pragma unroll
        for (int rg = 0; rg < 4; rg++) {
          int be = q2 * 4 + rg;
          float a0 = q2 ? s1[rg * 4 + 0] : s0[rg * 4 + 0];
          float a1 = q2 ? s1[rg * 4 + 1] : s0[rg * 4 + 1];
          float a2 = q2 ? s1[rg * 4 + 2] : s0[rg * 4 + 2];
          float a3 = q2 ? s1[rg * 4 + 3] : s0[rg * 4 + 3];
          pk[be][0] = (u32)f2b(a0) | ((u32)f2b(a1) << 16);
          pk[be][1] = (u32)f2b(a2) | ((u32)f2b(a3) << 16);
        }
      u32 pp[8][2];
#pragma unroll
      for (int be = 0; be < 8; be++) {
        pp[be][0] = (u32)__shfl_xor((int)pk[be][0], 32);
        pp[be][1] = (u32)__shfl_xor((int)pk[be][1], 32);
      }

#pragma unroll
      for (int kc = 0; kc < 4; kc++) {
        union { u32 wd[4]; bf16x8 v; } pb;
        if (hf == 0) {
          pb.wd[0] = pk[2 * kc][0];     pb.wd[1] = pk[2 * kc][1];
          pb.wd[2] = pp[2 * kc][0];     pb.wd[3] = pp[2 * kc][1];
        } else {
          pb.wd[0] = pp[2 * kc + 1][0]; pb.wd[1] = pp[2 * kc + 1][1];
          pb.wd[2] = pk[2 * kc + 1][0]; pb.wd[3] = pk[2 * kc + 1][1];
        }
        bf16x8 vf0 = ((const bf16x8*)Vts)[cl * 8 + ((2 * kc + hf) ^ (cl & 7))];
        bf16x8 vf1 = ((const bf16x8*)Vts)[(32 + cl) * 8 + ((2 * kc + hf) ^ (cl & 7))];
        o0 = __builtin_amdgcn_mfma_f32_32x32x16_bf16(vf0, pb.v, o0, 0, 0, 0);
        o1 = __builtin_amdgcn_mfma_f32_32x32x16_bf16(vf1, pb.v, o1, 0, 0, 0);
      }
      __syncthreads();
    }

    float rl = 1.f / l_i;
#pragma unroll
    for (int hq = 0; hq < 2; hq++)
#pragma unroll
      for (int rg = 0; rg < 4; rg++) {
        ushort4 st;
        st.x = f2b((hq ? o1[rg * 4 + 0] : o0[rg * 4 + 0]) * rl);
        st.y = f2b((hq ? o1[rg * 4 + 1] : o0[rg * 4 + 1]) * rl);
        st.z = f2b((hq ? o1[rg * 4 + 2] : o0[rg * 4 + 2]) * rl);
        st.w = f2b((hq ? o1[rg * 4 + 3] : o0[rg * 4 + 3]) * rl);
        int col = n * HDIM + hq * 32 + rg * 8 + 4 * hf;
        *(ushort4*)(ao + ((size_t)(b * TT + tq)) * DD + col) = st;
      }
  }
}

extern "C" void kernel_launch(void* const* d_in, const int* in_sizes, int n_in,
                              void* d_out, int out_size, void* d_ws, size_t ws_size,
                              hipStream_t stream) {
  const float* x   = (const float*)d_in[0];
  const float* pad = (const float*)d_in[1];
  const float* rs  = (const float*)d_in[2];
  const float* pds = (const float*)d_in[3];
  const float* wq  = (const float*)d_in[4];
  const float* bq  = (const float*)d_in[5];
  const float* wk  = (const float*)d_in[6];
  const float* bk  = (const float*)d_in[7];
  const float* wv_ = (const float*)d_in[8];
  const float* bv  = (const float*)d_in[9];
  const float* wo  = (const float*)d_in[10];
  const float* bo  = (const float*)d_in[11];
  const float* lg  = (const float*)d_in[12];
  const float* lb  = (const float*)d_in[13];
  const float* w1  = (const float*)d_in[14];
  const float* b1  = (const float*)d_in[15];
  const float* w2  = (const float*)d_in[16];
  const float* b2  = (const float*)d_in[17];
  float* out = (float*)d_out;   // fp32 output; also hosts the fp32 residual

  const size_t MB = (size_t)1 << 20;
  int G;
  if      (ws_size >= 88 * MB) G = 8;
  else if (ws_size >= 56 * MB) G = 4;
  else if (ws_size >= 40 * MB) G = 2;
  else                         G = 1;

  char* w = (char*)d_ws;
  u16* wqkvT = (u16*)(w);           // [3072][1024] bf16 = wqT|wkT|wvT contiguous
  u16* woT   = (u16*)(w + 6 * MB);  // [1024][1024]
  u16* w1T   = (u16*)(w + 8 * MB);  // [4096][1024]
  u16* w2T   = (u16*)(w + 16 * MB); // [1024][4096]
  char* act = w + 24 * MB;
  const size_t SA = (size_t)2 * G * MB;   // one region: G*1024 rows x 1024 bf16
  u16*   regA = (u16*)act;             // xn -> vT -> hn
  u16*   qB   = (u16*)(act + SA);      // q  (qB,kC,vD contiguous for fused QKV)
  u16*   kC   = (u16*)(act + 2 * SA);  // k
  u16*   vD   = (u16*)(act + 3 * SA);  // v -> ao
  u16*   vTr  = regA;
  u16*   ao   = vD;
  u16*   hn   = regA;
  u16*   h1h  = qB;                    // [R][2048] bf16 half-F activations (spans qB+kC)

  // small scratch in the tail of d_out (overwritten by final FFN2 afterwards)
  float* bqkv  = out + (size_t)out_size - 8192;
  float* qsall = bqkv + 3072;

  transpose_conv<<<dim3(32, 32),  256, 0, stream>>>(wq,  wqkvT,              DD, DD);
  transpose_conv<<<dim3(32, 32),  256, 0, stream>>>(wk,  wqkvT + 1024 * 1024, DD, DD);
  transpose_conv<<<dim3(32, 32),  256, 0, stream>>>(wv_, wqkvT + 2048 * 1024, DD, DD);
  conv_bf16<<<1024, 256, 0, stream>>>(wo, woT);
  transpose_conv<<<dim3(128, 32), 256, 0, stream>>>(w1, w1T, DD, FF);
  transpose_conv<<<dim3(32, 128), 256, 0, stream>>>(w2, w2T, FF, DD);
  prep_kernel<<<3, 1024, 0, stream>>>(bq, bk, bv, pds, bqkv, qsall);

  const int R = G * 1024;

  for (int c0 = 0; c0 < BB / G; c0++) {
    size_t rowoff = (size_t)c0 * R;
    const float* xc = x + rowoff * DD;
    float* outc = out + rowoff * DD;   // fp32 residual stream lives in d_out

    rms_kernel<<<R, 256, 0, stream>>>(xc, rs, regA);

    // fused QKV: N=3072 -> wide 128x256 grid (12, R/128); out via regstride
    mfma_gemm_wide<u16><<<dim3(12, R / 128), 256, 0, stream>>>(
        regA, wqkvT, bqkv, nullptr, qsall, qB,
        DD, DD, DD, 0, 1024, (size_t)R * 1024);

    vtrans_kernel<<<dim3(TT / 64, G * NHEAD), 256, 0, stream>>>(vD, vTr);

    attn_mfma<<<dim3(4, G * NHEAD), 256, 0, stream>>>(
        qB, kC, vTr, pad + rowoff, ao);

    // o-proj: outc = ao @ wo^T + bo + x   (128^2, 512-block grid)
    mfma_gemm<float><<<dim3(8, R / 128), 256, 0, stream>>>(
        ao, woT, bo, xc, nullptr, outc, DD, DD, DD, 0, 1024, 0);

    ln_kernel<<<R, 256, 0, stream>>>(outc, lg, lb, hn);

    // FFN: FFN1 wide 128x256 (grid (8, R/128) = 512 blocks); FFN2 128^2
    for (int f = 0; f < 2; f++) {
      mfma_gemm_wide<u16><<<dim3(8, R / 128), 256, 0, stream>>>(
          hn, w1T + (size_t)f * 2048 * 1024, b1 + f * 2048, nullptr, nullptr,
          h1h, DD, DD, DD, 1, 2048, 0);
      mfma_gemm<float><<<dim3(8, R / 128), 256, 0, stream>>>(
          h1h, w2T + f * 2048, (f == 0) ? b2 : nullptr, outc, nullptr,
          outc, 2048, FF, 2048, 0, 1024, 0);
    }
  }
}

// Round 11
// 555.365 us; speedup vs baseline: 1.2690x; 1.2690x over previous
//
#include <hip/hip_runtime.h>
#include <hip/hip_bf16.h>
#include <cstdint>
#include <cstddef>

#define BB    8
#define TT    1024
#define DD    1024
#define NHEAD 16
#define HDIM  64
#define FF    4096

typedef unsigned short u16;
typedef unsigned int   u32;
typedef short bf16x8 __attribute__((ext_vector_type(8)));
typedef float floatx4 __attribute__((ext_vector_type(4)));
typedef float floatx16 __attribute__((ext_vector_type(16)));
typedef __attribute__((address_space(1))) const u32 gu32;
typedef __attribute__((address_space(3))) u32 lu32;

#define ZERO16 {0.f,0.f,0.f,0.f,0.f,0.f,0.f,0.f,0.f,0.f,0.f,0.f,0.f,0.f,0.f,0.f}

__device__ __forceinline__ float b2f(u16 u) {
  union { u32 i; float f; } c; c.i = ((u32)u) << 16; return c.f;
}
__device__ __forceinline__ u16 f2b(float f) {
  union { float f; u32 i; } c; c.f = f;
  u32 x = c.i;
  u32 r = (x + 0x7fffu + ((x >> 16) & 1u)) >> 16;
  return (u16)r;
}

// ---------------- RMSNorm ----------------
__global__ __launch_bounds__(256) void rms_kernel(const float* __restrict__ x,
                                                  const float* __restrict__ g,
                                                  u16* __restrict__ xn) {
  int row = blockIdx.x;
  int tid = threadIdx.x;
  float4 v = ((const float4*)(x + (size_t)row * DD))[tid];
  float ss = v.x*v.x + v.y*v.y + v.z*v.z + v.w*v.w;
  for (int off = 32; off; off >>= 1) ss += __shfl_xor(ss, off);
  __shared__ float red[4];
  if ((tid & 63) == 0) red[tid >> 6] = ss;
  __syncthreads();
  float tot = red[0] + red[1] + red[2] + red[3];
  float inv = rsqrtf(tot * (1.0f / DD) + 1e-6f);
  float4 gv = ((const float4*)g)[tid];
  ushort4 o;
  o.x = f2b(v.x * inv * gv.x);
  o.y = f2b(v.y * inv * gv.y);
  o.z = f2b(v.z * inv * gv.z);
  o.w = f2b(v.w * inv * gv.w);
  ((ushort4*)(xn + (size_t)row * DD))[tid] = o;
}

// ---------------- LayerNorm (fp32 in, bf16 out) ----------------
__global__ __launch_bounds__(256) void ln_kernel(const float* __restrict__ a,
                                                 const float* __restrict__ g,
                                                 const float* __restrict__ be,
                                                 u16* __restrict__ o) {
  int row = blockIdx.x;
  int tid = threadIdx.x;
  float4 v = ((const float4*)(a + (size_t)row * DD))[tid];
  float s1 = v.x + v.y + v.z + v.w;
  float s2 = v.x*v.x + v.y*v.y + v.z*v.z + v.w*v.w;
  for (int off = 32; off; off >>= 1) {
    s1 += __shfl_xor(s1, off);
    s2 += __shfl_xor(s2, off);
  }
  __shared__ float r1[4], r2[4];
  if ((tid & 63) == 0) { r1[tid >> 6] = s1; r2[tid >> 6] = s2; }
  __syncthreads();
  float S1 = r1[0] + r1[1] + r1[2] + r1[3];
  float S2 = r2[0] + r2[1] + r2[2] + r2[3];
  float mean = S1 * (1.0f / DD);
  float var  = S2 * (1.0f / DD) - mean * mean;
  float inv  = rsqrtf(var + 1e-5f);
  float4 gv = ((const float4*)g)[tid];
  float4 bv = ((const float4*)be)[tid];
  ushort4 out;
  out.x = f2b((v.x - mean) * inv * gv.x + bv.x);
  out.y = f2b((v.y - mean) * inv * gv.y + bv.y);
  out.z = f2b((v.z - mean) * inv * gv.z + bv.z);
  out.w = f2b((v.w - mean) * inv * gv.w + bv.w);
  ((ushort4*)(o + (size_t)row * DD))[tid] = out;
}

// ------------- per-column bias+scale arrays for fused QKV -------------
// NOTE: q-scale carries an EXTRA log2(e) factor: softmax is computed in
// exp2 domain inside attn_mfma (exp(s) == exp2(s*log2e)).
__global__ void prep_kernel(const float* __restrict__ bq, const float* __restrict__ bk,
                            const float* __restrict__ bv, const float* __restrict__ pds,
                            float* __restrict__ bqkv, float* __restrict__ qsall) {
  int j = blockIdx.x * 1024 + threadIdx.x;  // 3 blocks x 1024
  float b = (j < 1024) ? bq[j] : (j < 2048) ? bk[j - 1024] : bv[j - 2048];
  bqkv[j] = b;
  float s = 1.f;
  if (j < 1024) {
    float p = pds[j & 63];
    float sp = (p > 0.f) ? (p + log1pf(__expf(-p))) : log1pf(__expf(p));
    s = 0.26017112252f * sp;  // (LOG2E^2)/sqrt(64) * softplus  (exp2-domain)
  }
  qsall[j] = s;
}

// ------------- fused 3-matrix transpose+convert (wq|wk|wv -> wqkvT) ----------
// in[z][R][C] fp32 -> out[z*C*R + c*R + r] bf16, z = blockIdx.z in {0,1,2}
__global__ __launch_bounds__(256) void transpose_conv3(const float* __restrict__ in0,
                                                       const float* __restrict__ in1,
                                                       const float* __restrict__ in2,
                                                       u16* __restrict__ out,
                                                       int R, int C) {
  __shared__ float t[32][33];
  const float* in = (blockIdx.z == 0) ? in0 : (blockIdx.z == 1) ? in1 : in2;
  u16* o = out + (size_t)blockIdx.z * R * C;
  int bx = blockIdx.x * 32, by = blockIdx.y * 32;
  int tx = threadIdx.x & 31, ty = threadIdx.x >> 5;  // 32 x 8
#pragma unroll
  for (int i = 0; i < 32; i += 8)
    t[ty + i][tx] = in[(size_t)(by + ty + i) * C + bx + tx];
  __syncthreads();
#pragma unroll
  for (int i = 0; i < 32; i += 8)
    o[(size_t)(bx + ty + i) * R + by + tx] = f2b(t[tx][ty + i]);
}

// ------------- weight transpose+convert: in[R][C] fp32 -> out[C][R] bf16 -------
__global__ __launch_bounds__(256) void transpose_conv(const float* __restrict__ in,
                                                      u16* __restrict__ out,
                                                      int R, int C) {
  __shared__ float t[32][33];
  int bx = blockIdx.x * 32, by = blockIdx.y * 32;
  int tx = threadIdx.x & 31, ty = threadIdx.x >> 5;  // 32 x 8
#pragma unroll
  for (int i = 0; i < 32; i += 8)
    t[ty + i][tx] = in[(size_t)(by + ty + i) * C + bx + tx];
  __syncthreads();
#pragma unroll
  for (int i = 0; i < 32; i += 8)
    out[(size_t)(bx + ty + i) * R + by + tx] = f2b(t[tx][ty + i]);
}

// ------------- elementwise fp32 -> bf16 convert -------------
__global__ __launch_bounds__(256) void conv_bf16(const float* __restrict__ in,
                                                 u16* __restrict__ out) {
  int i = blockIdx.x * 256 + threadIdx.x;
  float4 v = ((const float4*)in)[i];
  ushort4 o = { f2b(v.x), f2b(v.y), f2b(v.z), f2b(v.w) };
  ((ushort4*)out)[i] = o;
}

// ------------- V transpose per (b,n): vdst[bn][h][t] = vsrc[b*T+t][n*64+h] ----
__global__ __launch_bounds__(256) void vtrans_kernel(const u16* __restrict__ vsrc,
                                                     u16* __restrict__ vdst) {
  __shared__ u16 tile[64][65];
  int bn = blockIdx.y; int b = bn >> 4, n = bn & 15;
  int t0 = blockIdx.x * 64;
  int tid = threadIdx.x;
  int rr = tid >> 4;
  int c4 = (tid & 15) * 4;
#pragma unroll
  for (int i = 0; i < 4; i++) {
    int r = i * 16 + rr;
    ushort4 d = *(const ushort4*)(vsrc + ((size_t)(b * TT + t0 + r)) * DD + n * HDIM + c4);
    tile[r][c4 + 0] = d.x; tile[r][c4 + 1] = d.y;
    tile[r][c4 + 2] = d.z; tile[r][c4 + 3] = d.w;
  }
  __syncthreads();
#pragma unroll
  for (int i = 0; i < 4; i++) {
    int h = i * 16 + rr;
    ushort4 d;
    d.x = tile[c4 + 0][h]; d.y = tile[c4 + 1][h];
    d.z = tile[c4 + 2][h]; d.w = tile[c4 + 3][h];
    *(ushort4*)(vdst + ((size_t)bn * HDIM + h) * TT + t0 + c4) = d;
  }
}

// ---------------- MFMA GEMM (128^2, BK=64, round-7 proven; +4 blocks/CU) -----
// __launch_bounds__(256, 4): request 4 waves/SIMD -> allocator caps at 128
// regs/wave (64 AGPR acc + ~64 arch VGPR). If it fits -> 16 waves/CU (was 12).
// Spill (if any) only affects speed, not correctness.
template <typename OUT_T>
__global__ __launch_bounds__(256, 4) void mfma_gemm(
    const u16* __restrict__ A, const u16* __restrict__ Bt,
    const float* __restrict__ bias, const float* __restrict__ accsrc,
    const float* __restrict__ scale, OUT_T* __restrict__ C,
    int lda, int ldb, int K, int relu, int ldc, size_t regstride) {
  __shared__ u16 As[2][128 * 32] __attribute__((aligned(16)));
  __shared__ u16 Bs[2][128 * 32] __attribute__((aligned(16)));
  int tid = threadIdx.x;
  int lane = tid & 63;
  int wave = tid >> 6;
  int nbx = gridDim.x;
  int nwg = nbx * gridDim.y;
  int bid = blockIdx.y * nbx + blockIdx.x;
  int wid = (bid & 7) * (nwg >> 3) + (bid >> 3);
  int row0 = (wid / nbx) * 128, col0 = (wid % nbx) * 128;

  int sr = tid >> 2;
  int sk = (tid & 3) << 3;
  const u16* ag = A  + (size_t)(row0 + sr) * lda + sk;
  const u16* bg = Bt + (size_t)(col0 + sr) * ldb + sk;
  size_t rstepA = (size_t)64 * lda;
  size_t rstepB = (size_t)64 * ldb;

  int wr = (wave >> 1) * 64;
  int wc = (wave & 1) * 64;
  int fr = lane & 15;
  int fq = lane >> 4;

  floatx4 acc[4][4];
#pragma unroll
  for (int mi = 0; mi < 4; mi++)
#pragma unroll
    for (int ni = 0; ni < 4; ni++)
      acc[mi][ni] = (floatx4){0.f, 0.f, 0.f, 0.f};

  for (int k0 = 0; k0 < K; k0 += 64) {
#pragma unroll
    for (int kk = 0; kk < 2; kk++) {
      const u16* a_ = ag + kk * 32;
      const u16* b_ = bg + kk * 32;
      u16* asl = As[kk] + tid * 8;
      u16* bsl = Bs[kk] + tid * 8;
      __builtin_amdgcn_global_load_lds((gu32*)a_,            (lu32*)asl,          16, 0, 0);
      __builtin_amdgcn_global_load_lds((gu32*)(a_ + rstepA), (lu32*)(asl + 2048), 16, 0, 0);
      __builtin_amdgcn_global_load_lds((gu32*)b_,            (lu32*)bsl,          16, 0, 0);
      __builtin_amdgcn_global_load_lds((gu32*)(b_ + rstepB), (lu32*)(bsl + 2048), 16, 0, 0);
    }
    __syncthreads();
#pragma unroll
    for (int kk = 0; kk < 2; kk++) {
      const bf16x8* afp = (const bf16x8*)(As[kk] + (size_t)(wr + fr) * 32 + fq * 8);
      const bf16x8* bfp = (const bf16x8*)(Bs[kk] + (size_t)(wc + fr) * 32 + fq * 8);
      bf16x8 af[4], bf[4];
#pragma unroll
      for (int mi = 0; mi < 4; mi++) af[mi] = afp[mi * 64];
#pragma unroll
      for (int ni = 0; ni < 4; ni++) bf[ni] = bfp[ni * 64];
#pragma unroll
      for (int mi = 0; mi < 4; mi++)
#pragma unroll
        for (int ni = 0; ni < 4; ni++)
          acc[mi][ni] = __builtin_amdgcn_mfma_f32_16x16x32_bf16(
              af[mi], bf[ni], acc[mi][ni], 0, 0, 0);
    }
    __syncthreads();
    ag += 64; bg += 64;
  }

#pragma unroll
  for (int mi = 0; mi < 4; mi++) {
    int rbase = row0 + wr + mi * 16 + fq * 4;
#pragma unroll
    for (int ni = 0; ni < 4; ni++) {
      int col = col0 + wc + ni * 16 + fr;
      float bcol = bias ? bias[col] : 0.f;
      float scl  = scale ? scale[col] : 1.f;
      size_t cbase = regstride ? ((size_t)(col >> 10) * regstride + (col & 1023))
                               : (size_t)col;
#pragma unroll
      for (int reg = 0; reg < 4; reg++) {
        int r = rbase + reg;
        float v = (acc[mi][ni][reg] + bcol) * scl;
        if (relu)   v = fmaxf(v, 0.f);
        if (accsrc) v += accsrc[(size_t)r * ldc + col];
        if constexpr (sizeof(OUT_T) == 2) ((u16*)C)[cbase + (size_t)r * ldc] = f2b(v);
        else                              ((float*)C)[cbase + (size_t)r * ldc] = v;
      }
    }
  }
}

// ---------------- MFMA flash attention (balanced q-tile pairs) ----------------
__global__ __launch_bounds__(256) void attn_mfma(
    const u16* __restrict__ q, const u16* __restrict__ k,
    const u16* __restrict__ vT, const float* __restrict__ padc,
    u16* __restrict__ ao) {
  int nwg = gridDim.x * gridDim.y;        // 4 * G*16, %8 == 0
  int bid = blockIdx.y * gridDim.x + blockIdx.x;
  int wid = (bid & 7) * (nwg >> 3) + (bid >> 3);
  int p  = wid & 3;
  int bn = wid >> 2;
  int b = bn >> 4, n = bn & 15;
  int tid = threadIdx.x;
  int w = tid >> 6, lane = tid & 63;
  int cl = lane & 31, hf = lane >> 5;
  __shared__ u16 Qs[128 * 64] __attribute__((aligned(16)));
  __shared__ u16 Ks[64 * 64]  __attribute__((aligned(16)));
  __shared__ u16 Vts[64 * 64] __attribute__((aligned(16)));
  __shared__ float padl[64];

  for (int half = 0; half < 2; half++) {
    int qt = half ? (7 - p) : p;
    int q0g = qt * 128;

#pragma unroll
    for (int it = 0; it < 4; it++) {
      int cid = it * 256 + tid; int r = cid >> 3, cc = cid & 7;
      uint4 d = *(const uint4*)(q + ((size_t)(b * TT + q0g + r)) * DD + n * HDIM + cc * 8);
      ((uint4*)Qs)[r * 8 + (cc ^ (r & 7))] = d;
    }
    __syncthreads();
    bf16x8 qf[4];
    int qrow = 32 * w + cl;
#pragma unroll
    for (int kc = 0; kc < 4; kc++)
      qf[kc] = ((const bf16x8*)Qs)[qrow * 8 + ((2 * kc + hf) ^ (cl & 7))];

    int tq = q0g + qrow;
    float prow = padc[b * TT + tq];
    bool prow_ok = (prow != 0.f);
    floatx16 o0 = ZERO16, o1 = ZERO16;
    float m_i = -INFINITY, l_i = 0.f;

    int jend = q0g + 128;
    for (int j0 = 0; j0 < jend; j0 += 64) {
#pragma unroll
      for (int it = 0; it < 2; it++) {
        int cid = it * 256 + tid; int r = cid >> 3, cc = cid & 7;
        uint4 dk = *(const uint4*)(k + ((size_t)(b * TT + j0 + r)) * DD + n * HDIM + cc * 8);
        ((uint4*)Ks)[r * 8 + (cc ^ (r & 7))] = dk;
        uint4 dv = *(const uint4*)(vT + ((size_t)(bn * HDIM + r)) * TT + j0 + cc * 8);
        ((uint4*)Vts)[r * 8 + (cc ^ (r & 7))] = dv;
      }
      if (tid < 64) padl[tid] = padc[b * TT + j0 + tid];
      __syncthreads();

      floatx16 s0 = ZERO16, s1 = ZERO16;
#pragma unroll
      for (int kc = 0; kc < 4; kc++) {
        bf16x8 ka0 = ((const bf16x8*)Ks)[cl * 8 + ((2 * kc + hf) ^ (cl & 7))];
        bf16x8 ka1 = ((const bf16x8*)Ks)[(32 + cl) * 8 + ((2 * kc + hf) ^ (cl & 7))];
        s0 = __builtin_amdgcn_mfma_f32_32x32x16_bf16(ka0, qf[kc], s0, 0, 0, 0);
        s1 = __builtin_amdgcn_mfma_f32_32x32x16_bf16(ka1, qf[kc], s1, 0, 0, 0);
      }

      float pl = padl[lane];
      bool fullt = (j0 + 63 <= q0g + 32 * w) && __all(pl != 0.f) && __all((int)prow_ok);
      float mloc = -INFINITY;
      if (fullt) {
#pragma unroll
        for (int i = 0; i < 16; i++)
          mloc = fmaxf(mloc, fmaxf(s0[i], s1[i]));
      } else {
#pragma unroll
        for (int q2 = 0; q2 < 2; q2++) {
#pragma unroll
          for (int rg = 0; rg < 4; rg++) {
            float4 pv = *(const float4*)&padl[q2 * 32 + rg * 8 + 4 * hf];
            int kb = j0 + q2 * 32 + rg * 8 + 4 * hf;
#pragma unroll
            for (int j = 0; j < 4; j++) {
              int idx = rg * 4 + j;
              float sval = q2 ? s1[idx] : s0[idx];
              float pvj = (j == 0) ? pv.x : (j == 1) ? pv.y : (j == 2) ? pv.z : pv.w;
              bool ok = prow_ok && (kb + j <= tq) && (pvj != 0.f);
              sval = ok ? sval : -1e9f;
              if (q2) s1[idx] = sval; else s0[idx] = sval;
              mloc = fmaxf(mloc, sval);
            }
          }
        }
      }
      float mtile = fmaxf(mloc, __shfl_xor(mloc, 32));
      float mnew = fmaxf(m_i, mtile);
      float alpha = exp2f(m_i - mnew);
      m_i = mnew;
      float ls = 0.f;
#pragma unroll
      for (int i = 0; i < 16; i++) {
        float p0 = exp2f(s0[i] - mnew); s0[i] = p0; ls += p0;
        float p1 = exp2f(s1[i] - mnew); s1[i] = p1; ls += p1;
      }
      ls += __shfl_xor(ls, 32);
      l_i = l_i * alpha + ls;
      o0 *= alpha; o1 *= alpha;

      u32 pk[8][2];
#pragma unroll
      for (int q2 = 0; q2 < 2; q2++)
#pragma unroll
        for (int rg = 0; rg < 4; rg++) {
          int be = q2 * 4 + rg;
          float a0 = q2 ? s1[rg * 4 + 0] : s0[rg * 4 + 0];
          float a1 = q2 ? s1[rg * 4 + 1] : s0[rg * 4 + 1];
          float a2 = q2 ? s1[rg * 4 + 2] : s0[rg * 4 + 2];
          float a3 = q2 ? s1[rg * 4 + 3] : s0[rg * 4 + 3];
          pk[be][0] = (u32)f2b(a0) | ((u32)f2b(a1) << 16);
          pk[be][1] = (u32)f2b(a2) | ((u32)f2b(a3) << 16);
        }
      u32 pp[8][2];
#pragma unroll
      for (int be = 0; be < 8; be++) {
        pp[be][0] = (u32)__shfl_xor((int)pk[be][0], 32);
        pp[be][1] = (u32)__shfl_xor((int)pk[be][1], 32);
      }

#pragma unroll
      for (int kc = 0; kc < 4; kc++) {
        union { u32 wd[4]; bf16x8 v; } pb;
        if (hf == 0) {
          pb.wd[0] = pk[2 * kc][0];     pb.wd[1] = pk[2 * kc][1];
          pb.wd[2] = pp[2 * kc][0];     pb.wd[3] = pp[2 * kc][1];
        } else {
          pb.wd[0] = pp[2 * kc + 1][0]; pb.wd[1] = pp[2 * kc + 1][1];
          pb.wd[2] = pk[2 * kc + 1][0]; pb.wd[3] = pk[2 * kc + 1][1];
        }
        bf16x8 vf0 = ((const bf16x8*)Vts)[cl * 8 + ((2 * kc + hf) ^ (cl & 7))];
        bf16x8 vf1 = ((const bf16x8*)Vts)[(32 + cl) * 8 + ((2 * kc + hf) ^ (cl & 7))];
        o0 = __builtin_amdgcn_mfma_f32_32x32x16_bf16(vf0, pb.v, o0, 0, 0, 0);
        o1 = __builtin_amdgcn_mfma_f32_32x32x16_bf16(vf1, pb.v, o1, 0, 0, 0);
      }
      __syncthreads();
    }

    float rl = 1.f / l_i;
#pragma unroll
    for (int hq = 0; hq < 2; hq++)
#pragma unroll
      for (int rg = 0; rg < 4; rg++) {
        ushort4 st;
        st.x = f2b((hq ? o1[rg * 4 + 0] : o0[rg * 4 + 0]) * rl);
        st.y = f2b((hq ? o1[rg * 4 + 1] : o0[rg * 4 + 1]) * rl);
        st.z = f2b((hq ? o1[rg * 4 + 2] : o0[rg * 4 + 2]) * rl);
        st.w = f2b((hq ? o1[rg * 4 + 3] : o0[rg * 4 + 3]) * rl);
        int col = n * HDIM + hq * 32 + rg * 8 + 4 * hf;
        *(ushort4*)(ao + ((size_t)(b * TT + tq)) * DD + col) = st;
      }
  }
}

extern "C" void kernel_launch(void* const* d_in, const int* in_sizes, int n_in,
                              void* d_out, int out_size, void* d_ws, size_t ws_size,
                              hipStream_t stream) {
  const float* x   = (const float*)d_in[0];
  const float* pad = (const float*)d_in[1];
  const float* rs  = (const float*)d_in[2];
  const float* pds = (const float*)d_in[3];
  const float* wq  = (const float*)d_in[4];
  const float* bq  = (const float*)d_in[5];
  const float* wk  = (const float*)d_in[6];
  const float* bk  = (const float*)d_in[7];
  const float* wv_ = (const float*)d_in[8];
  const float* bv  = (const float*)d_in[9];
  const float* wo  = (const float*)d_in[10];
  const float* bo  = (const float*)d_in[11];
  const float* lg  = (const float*)d_in[12];
  const float* lb  = (const float*)d_in[13];
  const float* w1  = (const float*)d_in[14];
  const float* b1  = (const float*)d_in[15];
  const float* w2  = (const float*)d_in[16];
  const float* b2  = (const float*)d_in[17];
  float* out = (float*)d_out;   // fp32 output; also hosts the fp32 residual

  const size_t MB = (size_t)1 << 20;
  int G;
  if      (ws_size >= 88 * MB) G = 8;
  else if (ws_size >= 56 * MB) G = 4;
  else if (ws_size >= 40 * MB) G = 2;
  else                         G = 1;

  char* w = (char*)d_ws;
  u16* wqkvT = (u16*)(w);           // [3072][1024] bf16 = wqT|wkT|wvT contiguous
  u16* woT   = (u16*)(w + 6 * MB);  // [1024][1024]
  u16* w1T   = (u16*)(w + 8 * MB);  // [4096][1024]
  u16* w2T   = (u16*)(w + 16 * MB); // [1024][4096]
  char* act = w + 24 * MB;
  const size_t SA = (size_t)2 * G * MB;   // one region: G*1024 rows x 1024 bf16
  u16*   regA = (u16*)act;             // xn -> vT -> hn
  u16*   qB   = (u16*)(act + SA);      // q  (qB,kC,vD contiguous for fused QKV)
  u16*   kC   = (u16*)(act + 2 * SA);  // k
  u16*   vD   = (u16*)(act + 3 * SA);  // v -> ao
  u16*   vTr  = regA;
  u16*   ao   = vD;
  u16*   hn   = regA;
  u16*   h1h  = qB;                    // [R][2048] bf16 half-F activations (spans qB+kC)

  // small scratch in the tail of d_out (overwritten by final FFN2 afterwards)
  float* bqkv  = out + (size_t)out_size - 8192;
  float* qsall = bqkv + 3072;

  transpose_conv3<<<dim3(32, 32, 3), 256, 0, stream>>>(wq, wk, wv_, wqkvT, DD, DD);
  conv_bf16<<<1024, 256, 0, stream>>>(wo, woT);
  transpose_conv<<<dim3(128, 32), 256, 0, stream>>>(w1, w1T, DD, FF);
  transpose_conv<<<dim3(32, 128), 256, 0, stream>>>(w2, w2T, FF, DD);
  prep_kernel<<<3, 1024, 0, stream>>>(bq, bk, bv, pds, bqkv, qsall);

  const int R = G * 1024;

  for (int c0 = 0; c0 < BB / G; c0++) {
    size_t rowoff = (size_t)c0 * R;
    const float* xc = x + rowoff * DD;
    float* outc = out + rowoff * DD;   // fp32 residual stream lives in d_out

    rms_kernel<<<R, 256, 0, stream>>>(xc, rs, regA);

    // fused QKV: N=3072 -> grid (24, R/128); out regions qB/kC/vD via regstride
    mfma_gemm<u16><<<dim3(24, R / 128), 256, 0, stream>>>(
        regA, wqkvT, bqkv, nullptr, qsall, qB,
        DD, DD, DD, 0, 1024, (size_t)R * 1024);

    vtrans_kernel<<<dim3(TT / 64, G * NHEAD), 256, 0, stream>>>(vD, vTr);

    attn_mfma<<<dim3(4, G * NHEAD), 256, 0, stream>>>(
        qB, kC, vTr, pad + rowoff, ao);

    // o-proj: outc = ao @ wo^T + bo + x   (fp32 residual into d_out)
    mfma_gemm<float><<<dim3(8, R / 128), 256, 0, stream>>>(
        ao, woT, bo, xc, nullptr, outc, DD, DD, DD, 0, 1024, 0);

    ln_kernel<<<R, 256, 0, stream>>>(outc, lg, lb, hn);

    // FFN in 2 half-F panels: FFN1 N=2048 (ldc=2048), FFN2 K=2048 RMW residual
    for (int f = 0; f < 2; f++) {
      mfma_gemm<u16><<<dim3(16, R / 128), 256, 0, stream>>>(
          hn, w1T + (size_t)f * 2048 * 1024, b1 + f * 2048, nullptr, nullptr,
          h1h, DD, DD, DD, 1, 2048, 0);
      mfma_gemm<float><<<dim3(8, R / 128), 256, 0, stream>>>(
          h1h, w2T + f * 2048, (f == 0) ? b2 : nullptr, outc, nullptr,
          outc, 2048, FF, 2048, 0, 1024, 0);
    }
  }
}

// Round 12
// 554.252 us; speedup vs baseline: 1.2715x; 1.0020x over previous
//
#include <hip/hip_runtime.h>
#include <hip/hip_bf16.h>
#include <cstdint>
#include <cstddef>

#define BB    8
#define TT    1024
#define DD    1024
#define NHEAD 16
#define HDIM  64
#define FF    4096

typedef unsigned short u16;
typedef unsigned int   u32;
typedef short bf16x8 __attribute__((ext_vector_type(8)));
typedef float floatx4 __attribute__((ext_vector_type(4)));
typedef float floatx16 __attribute__((ext_vector_type(16)));
typedef __attribute__((address_space(1))) const u32 gu32;
typedef __attribute__((address_space(3))) u32 lu32;

#define ZERO16 {0.f,0.f,0.f,0.f,0.f,0.f,0.f,0.f,0.f,0.f,0.f,0.f,0.f,0.f,0.f,0.f}

__device__ __forceinline__ float b2f(u16 u) {
  union { u32 i; float f; } c; c.i = ((u32)u) << 16; return c.f;
}
__device__ __forceinline__ u16 f2b(float f) {
  union { float f; u32 i; } c; c.f = f;
  u32 x = c.i;
  u32 r = (x + 0x7fffu + ((x >> 16) & 1u)) >> 16;
  return (u16)r;
}

// ---------------- RMSNorm ----------------
__global__ __launch_bounds__(256) void rms_kernel(const float* __restrict__ x,
                                                  const float* __restrict__ g,
                                                  u16* __restrict__ xn) {
  int row = blockIdx.x;
  int tid = threadIdx.x;
  float4 v = ((const float4*)(x + (size_t)row * DD))[tid];
  float ss = v.x*v.x + v.y*v.y + v.z*v.z + v.w*v.w;
  for (int off = 32; off; off >>= 1) ss += __shfl_xor(ss, off);
  __shared__ float red[4];
  if ((tid & 63) == 0) red[tid >> 6] = ss;
  __syncthreads();
  float tot = red[0] + red[1] + red[2] + red[3];
  float inv = rsqrtf(tot * (1.0f / DD) + 1e-6f);
  float4 gv = ((const float4*)g)[tid];
  ushort4 o;
  o.x = f2b(v.x * inv * gv.x);
  o.y = f2b(v.y * inv * gv.y);
  o.z = f2b(v.z * inv * gv.z);
  o.w = f2b(v.w * inv * gv.w);
  ((ushort4*)(xn + (size_t)row * DD))[tid] = o;
}

// ---------------- LayerNorm (fp32 in, bf16 out) ----------------
__global__ __launch_bounds__(256) void ln_kernel(const float* __restrict__ a,
                                                 const float* __restrict__ g,
                                                 const float* __restrict__ be,
                                                 u16* __restrict__ o) {
  int row = blockIdx.x;
  int tid = threadIdx.x;
  float4 v = ((const float4*)(a + (size_t)row * DD))[tid];
  float s1 = v.x + v.y + v.z + v.w;
  float s2 = v.x*v.x + v.y*v.y + v.z*v.z + v.w*v.w;
  for (int off = 32; off; off >>= 1) {
    s1 += __shfl_xor(s1, off);
    s2 += __shfl_xor(s2, off);
  }
  __shared__ float r1[4], r2[4];
  if ((tid & 63) == 0) { r1[tid >> 6] = s1; r2[tid >> 6] = s2; }
  __syncthreads();
  float S1 = r1[0] + r1[1] + r1[2] + r1[3];
  float S2 = r2[0] + r2[1] + r2[2] + r2[3];
  float mean = S1 * (1.0f / DD);
  float var  = S2 * (1.0f / DD) - mean * mean;
  float inv  = rsqrtf(var + 1e-5f);
  float4 gv = ((const float4*)g)[tid];
  float4 bv = ((const float4*)be)[tid];
  ushort4 out;
  out.x = f2b((v.x - mean) * inv * gv.x + bv.x);
  out.y = f2b((v.y - mean) * inv * gv.y + bv.y);
  out.z = f2b((v.z - mean) * inv * gv.z + bv.z);
  out.w = f2b((v.w - mean) * inv * gv.w + bv.w);
  ((ushort4*)(o + (size_t)row * DD))[tid] = out;
}

// ------------- per-column bias+scale arrays for fused QKV -------------
// NOTE: q-scale carries an EXTRA log2(e) factor: softmax is computed in
// exp2 domain inside attn_mfma (exp(s) == exp2(s*log2e)).
__global__ void prep_kernel(const float* __restrict__ bq, const float* __restrict__ bk,
                            const float* __restrict__ bv, const float* __restrict__ pds,
                            float* __restrict__ bqkv, float* __restrict__ qsall) {
  int j = blockIdx.x * 1024 + threadIdx.x;  // 3 blocks x 1024
  float b = (j < 1024) ? bq[j] : (j < 2048) ? bk[j - 1024] : bv[j - 2048];
  bqkv[j] = b;
  float s = 1.f;
  if (j < 1024) {
    float p = pds[j & 63];
    float sp = (p > 0.f) ? (p + log1pf(__expf(-p))) : log1pf(__expf(p));
    s = 0.26017112252f * sp;  // (LOG2E^2)/sqrt(64) * softplus  (exp2-domain)
  }
  qsall[j] = s;
}

// ------------- fused 3-matrix transpose+convert (wq|wk|wv -> wqkvT) ----------
__global__ __launch_bounds__(256) void transpose_conv3(const float* __restrict__ in0,
                                                       const float* __restrict__ in1,
                                                       const float* __restrict__ in2,
                                                       u16* __restrict__ out,
                                                       int R, int C) {
  __shared__ float t[32][33];
  const float* in = (blockIdx.z == 0) ? in0 : (blockIdx.z == 1) ? in1 : in2;
  u16* o = out + (size_t)blockIdx.z * R * C;
  int bx = blockIdx.x * 32, by = blockIdx.y * 32;
  int tx = threadIdx.x & 31, ty = threadIdx.x >> 5;  // 32 x 8
#pragma unroll
  for (int i = 0; i < 32; i += 8)
    t[ty + i][tx] = in[(size_t)(by + ty + i) * C + bx + tx];
  __syncthreads();
#pragma unroll
  for (int i = 0; i < 32; i += 8)
    o[(size_t)(bx + ty + i) * R + by + tx] = f2b(t[tx][ty + i]);
}

// ------------- weight transpose+convert: in[R][C] fp32 -> out[C][R] bf16 -------
__global__ __launch_bounds__(256) void transpose_conv(const float* __restrict__ in,
                                                      u16* __restrict__ out,
                                                      int R, int C) {
  __shared__ float t[32][33];
  int bx = blockIdx.x * 32, by = blockIdx.y * 32;
  int tx = threadIdx.x & 31, ty = threadIdx.x >> 5;  // 32 x 8
#pragma unroll
  for (int i = 0; i < 32; i += 8)
    t[ty + i][tx] = in[(size_t)(by + ty + i) * C + bx + tx];
  __syncthreads();
#pragma unroll
  for (int i = 0; i < 32; i += 8)
    out[(size_t)(bx + ty + i) * R + by + tx] = f2b(t[tx][ty + i]);
}

// ------------- elementwise fp32 -> bf16 convert -------------
__global__ __launch_bounds__(256) void conv_bf16(const float* __restrict__ in,
                                                 u16* __restrict__ out) {
  int i = blockIdx.x * 256 + threadIdx.x;
  float4 v = ((const float4*)in)[i];
  ushort4 o = { f2b(v.x), f2b(v.y), f2b(v.z), f2b(v.w) };
  ((ushort4*)out)[i] = o;
}

// ------------- V transpose per (b,n): vdst[bn][h][t] = vsrc[b*T+t][n*64+h] ----
__global__ __launch_bounds__(256) void vtrans_kernel(const u16* __restrict__ vsrc,
                                                     u16* __restrict__ vdst) {
  __shared__ u16 tile[64][65];
  int bn = blockIdx.y; int b = bn >> 4, n = bn & 15;
  int t0 = blockIdx.x * 64;
  int tid = threadIdx.x;
  int rr = tid >> 4;
  int c4 = (tid & 15) * 4;
#pragma unroll
  for (int i = 0; i < 4; i++) {
    int r = i * 16 + rr;
    ushort4 d = *(const ushort4*)(vsrc + ((size_t)(b * TT + t0 + r)) * DD + n * HDIM + c4);
    tile[r][c4 + 0] = d.x; tile[r][c4 + 1] = d.y;
    tile[r][c4 + 2] = d.z; tile[r][c4 + 3] = d.w;
  }
  __syncthreads();
#pragma unroll
  for (int i = 0; i < 4; i++) {
    int h = i * 16 + rr;
    ushort4 d;
    d.x = tile[c4 + 0][h]; d.y = tile[c4 + 1][h];
    d.z = tile[c4 + 2][h]; d.w = tile[c4 + 3][h];
    *(ushort4*)(vdst + ((size_t)bn * HDIM + h) * TT + t0 + c4) = d;
  }
}

// ---------------- MFMA GEMM (128^2, BK=64, 4 blocks/CU, chunk-XOR swizzle) ---
// LDS bank-conflict fix (T2, rule #21: swizzle source+read, linear dest):
// 16B chunk c of row r lives at chunk position c^(r&3). Staging lane loads
// global chunk (tid&3)^(sr&3) (same 64B row -> coalescing intact; rows sr and
// sr+64 share the mask, K-subtile +32 cols preserves chunk structure).
// Fragment read uses chunk fq^(fr&3) (wr/wc are multiples of 64 -> row&3==fr&3;
// af[mi]'s +16-row stride also preserves fr&3). XOR is an involution, so the
// two permutations match. Spreads the former 8-way conflict to 4-way.
template <typename OUT_T>
__global__ __launch_bounds__(256, 4) void mfma_gemm(
    const u16* __restrict__ A, const u16* __restrict__ Bt,
    const float* __restrict__ bias, const float* __restrict__ accsrc,
    const float* __restrict__ scale, OUT_T* __restrict__ C,
    int lda, int ldb, int K, int relu, int ldc, size_t regstride) {
  __shared__ u16 As[2][128 * 32] __attribute__((aligned(16)));
  __shared__ u16 Bs[2][128 * 32] __attribute__((aligned(16)));
  int tid = threadIdx.x;
  int lane = tid & 63;
  int wave = tid >> 6;
  int nbx = gridDim.x;
  int nwg = nbx * gridDim.y;
  int bid = blockIdx.y * nbx + blockIdx.x;
  int wid = (bid & 7) * (nwg >> 3) + (bid >> 3);
  int row0 = (wid / nbx) * 128, col0 = (wid % nbx) * 128;

  int sr = tid >> 2;
  int sk = (((tid & 3) ^ (sr & 3)) << 3);   // pre-swizzled source chunk
  const u16* ag = A  + (size_t)(row0 + sr) * lda + sk;
  const u16* bg = Bt + (size_t)(col0 + sr) * ldb + sk;
  size_t rstepA = (size_t)64 * lda;
  size_t rstepB = (size_t)64 * ldb;

  int wr = (wave >> 1) * 64;
  int wc = (wave & 1) * 64;
  int fr = lane & 15;
  int fq = lane >> 4;
  int cs = (fq ^ (fr & 3)) * 8;             // swizzled read chunk (u16 units)

  floatx4 acc[4][4];
#pragma unroll
  for (int mi = 0; mi < 4; mi++)
#pragma unroll
    for (int ni = 0; ni < 4; ni++)
      acc[mi][ni] = (floatx4){0.f, 0.f, 0.f, 0.f};

  for (int k0 = 0; k0 < K; k0 += 64) {
#pragma unroll
    for (int kk = 0; kk < 2; kk++) {
      const u16* a_ = ag + kk * 32;
      const u16* b_ = bg + kk * 32;
      u16* asl = As[kk] + tid * 8;
      u16* bsl = Bs[kk] + tid * 8;
      __builtin_amdgcn_global_load_lds((gu32*)a_,            (lu32*)asl,          16, 0, 0);
      __builtin_amdgcn_global_load_lds((gu32*)(a_ + rstepA), (lu32*)(asl + 2048), 16, 0, 0);
      __builtin_amdgcn_global_load_lds((gu32*)b_,            (lu32*)bsl,          16, 0, 0);
      __builtin_amdgcn_global_load_lds((gu32*)(b_ + rstepB), (lu32*)(bsl + 2048), 16, 0, 0);
    }
    __syncthreads();
#pragma unroll
    for (int kk = 0; kk < 2; kk++) {
      const bf16x8* afp = (const bf16x8*)(As[kk] + (size_t)(wr + fr) * 32 + cs);
      const bf16x8* bfp = (const bf16x8*)(Bs[kk] + (size_t)(wc + fr) * 32 + cs);
      bf16x8 af[4], bf[4];
#pragma unroll
      for (int mi = 0; mi < 4; mi++) af[mi] = afp[mi * 64];
#pragma unroll
      for (int ni = 0; ni < 4; ni++) bf[ni] = bfp[ni * 64];
#pragma unroll
      for (int mi = 0; mi < 4; mi++)
#pragma unroll
        for (int ni = 0; ni < 4; ni++)
          acc[mi][ni] = __builtin_amdgcn_mfma_f32_16x16x32_bf16(
              af[mi], bf[ni], acc[mi][ni], 0, 0, 0);
    }
    __syncthreads();
    ag += 64; bg += 64;
  }

#pragma unroll
  for (int mi = 0; mi < 4; mi++) {
    int rbase = row0 + wr + mi * 16 + fq * 4;
#pragma unroll
    for (int ni = 0; ni < 4; ni++) {
      int col = col0 + wc + ni * 16 + fr;
      float bcol = bias ? bias[col] : 0.f;
      float scl  = scale ? scale[col] : 1.f;
      size_t cbase = regstride ? ((size_t)(col >> 10) * regstride + (col & 1023))
                               : (size_t)col;
#pragma unroll
      for (int reg = 0; reg < 4; reg++) {
        int r = rbase + reg;
        float v = (acc[mi][ni][reg] + bcol) * scl;
        if (relu)   v = fmaxf(v, 0.f);
        if (accsrc) v += accsrc[(size_t)r * ldc + col];
        if constexpr (sizeof(OUT_T) == 2) ((u16*)C)[cbase + (size_t)r * ldc] = f2b(v);
        else                              ((float*)C)[cbase + (size_t)r * ldc] = v;
      }
    }
  }
}

// ---------------- MFMA flash attention (balanced q-tile pairs) ----------------
__global__ __launch_bounds__(256) void attn_mfma(
    const u16* __restrict__ q, const u16* __restrict__ k,
    const u16* __restrict__ vT, const float* __restrict__ padc,
    u16* __restrict__ ao) {
  int nwg = gridDim.x * gridDim.y;        // 4 * G*16, %8 == 0
  int bid = blockIdx.y * gridDim.x + blockIdx.x;
  int wid = (bid & 7) * (nwg >> 3) + (bid >> 3);
  int p  = wid & 3;
  int bn = wid >> 2;
  int b = bn >> 4, n = bn & 15;
  int tid = threadIdx.x;
  int w = tid >> 6, lane = tid & 63;
  int cl = lane & 31, hf = lane >> 5;
  __shared__ u16 Qs[128 * 64] __attribute__((aligned(16)));
  __shared__ u16 Ks[64 * 64]  __attribute__((aligned(16)));
  __shared__ u16 Vts[64 * 64] __attribute__((aligned(16)));
  __shared__ float padl[64];

  for (int half = 0; half < 2; half++) {
    int qt = half ? (7 - p) : p;
    int q0g = qt * 128;

#pragma unroll
    for (int it = 0; it < 4; it++) {
      int cid = it * 256 + tid; int r = cid >> 3, cc = cid & 7;
      uint4 d = *(const uint4*)(q + ((size_t)(b * TT + q0g + r)) * DD + n * HDIM + cc * 8);
      ((uint4*)Qs)[r * 8 + (cc ^ (r & 7))] = d;
    }
    __syncthreads();
    bf16x8 qf[4];
    int qrow = 32 * w + cl;
#pragma unroll
    for (int kc = 0; kc < 4; kc++)
      qf[kc] = ((const bf16x8*)Qs)[qrow * 8 + ((2 * kc + hf) ^ (cl & 7))];

    int tq = q0g + qrow;
    float prow = padc[b * TT + tq];
    bool prow_ok = (prow != 0.f);
    floatx16 o0 = ZERO16, o1 = ZERO16;
    float m_i = -INFINITY, l_i = 0.f;

    int jend = q0g + 128;
    for (int j0 = 0; j0 < jend; j0 += 64) {
#pragma unroll
      for (int it = 0; it < 2; it++) {
        int cid = it * 256 + tid; int r = cid >> 3, cc = cid & 7;
        uint4 dk = *(const uint4*)(k + ((size_t)(b * TT + j0 + r)) * DD + n * HDIM + cc * 8);
        ((uint4*)Ks)[r * 8 + (cc ^ (r & 7))] = dk;
        uint4 dv = *(const uint4*)(vT + ((size_t)(bn * HDIM + r)) * TT + j0 + cc * 8);
        ((uint4*)Vts)[r * 8 + (cc ^ (r & 7))] = dv;
      }
      if (tid < 64) padl[tid] = padc[b * TT + j0 + tid];
      __syncthreads();

      floatx16 s0 = ZERO16, s1 = ZERO16;
#pragma unroll
      for (int kc = 0; kc < 4; kc++) {
        bf16x8 ka0 = ((const bf16x8*)Ks)[cl * 8 + ((2 * kc + hf) ^ (cl & 7))];
        bf16x8 ka1 = ((const bf16x8*)Ks)[(32 + cl) * 8 + ((2 * kc + hf) ^ (cl & 7))];
        s0 = __builtin_amdgcn_mfma_f32_32x32x16_bf16(ka0, qf[kc], s0, 0, 0, 0);
        s1 = __builtin_amdgcn_mfma_f32_32x32x16_bf16(ka1, qf[kc], s1, 0, 0, 0);
      }

      float pl = padl[lane];
      bool fullt = (j0 + 63 <= q0g + 32 * w) && __all(pl != 0.f) && __all((int)prow_ok);
      float mloc = -INFINITY;
      if (fullt) {
#pragma unroll
        for (int i = 0; i < 16; i++)
          mloc = fmaxf(mloc, fmaxf(s0[i], s1[i]));
      } else {
#pragma unroll
        for (int q2 = 0; q2 < 2; q2++) {
#pragma unroll
          for (int rg = 0; rg < 4; rg++) {
            float4 pv = *(const float4*)&padl[q2 * 32 + rg * 8 + 4 * hf];
            int kb = j0 + q2 * 32 + rg * 8 + 4 * hf;
#pragma unroll
            for (int j = 0; j < 4; j++) {
              int idx = rg * 4 + j;
              float sval = q2 ? s1[idx] : s0[idx];
              float pvj = (j == 0) ? pv.x : (j == 1) ? pv.y : (j == 2) ? pv.z : pv.w;
              bool ok = prow_ok && (kb + j <= tq) && (pvj != 0.f);
              sval = ok ? sval : -1e9f;
              if (q2) s1[idx] = sval; else s0[idx] = sval;
              mloc = fmaxf(mloc, sval);
            }
          }
        }
      }
      float mtile = fmaxf(mloc, __shfl_xor(mloc, 32));
      float mnew = fmaxf(m_i, mtile);
      float alpha = exp2f(m_i - mnew);
      m_i = mnew;
      float ls = 0.f;
#pragma unroll
      for (int i = 0; i < 16; i++) {
        float p0 = exp2f(s0[i] - mnew); s0[i] = p0; ls += p0;
        float p1 = exp2f(s1[i] - mnew); s1[i] = p1; ls += p1;
      }
      ls += __shfl_xor(ls, 32);
      l_i = l_i * alpha + ls;
      o0 *= alpha; o1 *= alpha;

      u32 pk[8][2];
#pragma unroll
      for (int q2 = 0; q2 < 2; q2++)
#pragma unroll
        for (int rg = 0; rg < 4; rg++) {
          int be = q2 * 4 + rg;
          float a0 = q2 ? s1[rg * 4 + 0] : s0[rg * 4 + 0];
          float a1 = q2 ? s1[rg * 4 + 1] : s0[rg * 4 + 1];
          float a2 = q2 ? s1[rg * 4 + 2] : s0[rg * 4 + 2];
          float a3 = q2 ? s1[rg * 4 + 3] : s0[rg * 4 + 3];
          pk[be][0] = (u32)f2b(a0) | ((u32)f2b(a1) << 16);
          pk[be][1] = (u32)f2b(a2) | ((u32)f2b(a3) << 16);
        }
      u32 pp[8][2];
#pragma unroll
      for (int be = 0; be < 8; be++) {
        pp[be][0] = (u32)__shfl_xor((int)pk[be][0], 32);
        pp[be][1] = (u32)__shfl_xor((int)pk[be][1], 32);
      }

#pragma unroll
      for (int kc = 0; kc < 4; kc++) {
        union { u32 wd[4]; bf16x8 v; } pb;
        if (hf == 0) {
          pb.wd[0] = pk[2 * kc][0];     pb.wd[1] = pk[2 * kc][1];
          pb.wd[2] = pp[2 * kc][0];     pb.wd[3] = pp[2 * kc][1];
        } else {
          pb.wd[0] = pp[2 * kc + 1][0]; pb.wd[1] = pp[2 * kc + 1][1];
          pb.wd[2] = pk[2 * kc + 1][0]; pb.wd[3] = pk[2 * kc + 1][1];
        }
        bf16x8 vf0 = ((const bf16x8*)Vts)[cl * 8 + ((2 * kc + hf) ^ (cl & 7))];
        bf16x8 vf1 = ((const bf16x8*)Vts)[(32 + cl) * 8 + ((2 * kc + hf) ^ (cl & 7))];
        o0 = __builtin_amdgcn_mfma_f32_32x32x16_bf16(vf0, pb.v, o0, 0, 0, 0);
        o1 = __builtin_amdgcn_mfma_f32_32x32x16_bf16(vf1, pb.v, o1, 0, 0, 0);
      }
      __syncthreads();
    }

    float rl = 1.f / l_i;
#pragma unroll
    for (int hq = 0; hq < 2; hq++)
#pragma unroll
      for (int rg = 0; rg < 4; rg++) {
        ushort4 st;
        st.x = f2b((hq ? o1[rg * 4 + 0] : o0[rg * 4 + 0]) * rl);
        st.y = f2b((hq ? o1[rg * 4 + 1] : o0[rg * 4 + 1]) * rl);
        st.z = f2b((hq ? o1[rg * 4 + 2] : o0[rg * 4 + 2]) * rl);
        st.w = f2b((hq ? o1[rg * 4 + 3] : o0[rg * 4 + 3]) * rl);
        int col = n * HDIM + hq * 32 + rg * 8 + 4 * hf;
        *(ushort4*)(ao + ((size_t)(b * TT + tq)) * DD + col) = st;
      }
  }
}

extern "C" void kernel_launch(void* const* d_in, const int* in_sizes, int n_in,
                              void* d_out, int out_size, void* d_ws, size_t ws_size,
                              hipStream_t stream) {
  const float* x   = (const float*)d_in[0];
  const float* pad = (const float*)d_in[1];
  const float* rs  = (const float*)d_in[2];
  const float* pds = (const float*)d_in[3];
  const float* wq  = (const float*)d_in[4];
  const float* bq  = (const float*)d_in[5];
  const float* wk  = (const float*)d_in[6];
  const float* bk  = (const float*)d_in[7];
  const float* wv_ = (const float*)d_in[8];
  const float* bv  = (const float*)d_in[9];
  const float* wo  = (const float*)d_in[10];
  const float* bo  = (const float*)d_in[11];
  const float* lg  = (const float*)d_in[12];
  const float* lb  = (const float*)d_in[13];
  const float* w1  = (const float*)d_in[14];
  const float* b1  = (const float*)d_in[15];
  const float* w2  = (const float*)d_in[16];
  const float* b2  = (const float*)d_in[17];
  float* out = (float*)d_out;   // fp32 output; also hosts the fp32 residual

  const size_t MB = (size_t)1 << 20;
  int G;
  if      (ws_size >= 88 * MB) G = 8;
  else if (ws_size >= 56 * MB) G = 4;
  else if (ws_size >= 40 * MB) G = 2;
  else                         G = 1;

  char* w = (char*)d_ws;
  u16* wqkvT = (u16*)(w);           // [3072][1024] bf16 = wqT|wkT|wvT contiguous
  u16* woT   = (u16*)(w + 6 * MB);  // [1024][1024]
  u16* w1T   = (u16*)(w + 8 * MB);  // [4096][1024]
  u16* w2T   = (u16*)(w + 16 * MB); // [1024][4096]
  char* act = w + 24 * MB;
  const size_t SA = (size_t)2 * G * MB;   // one region: G*1024 rows x 1024 bf16
  u16*   regA = (u16*)act;             // xn -> vT -> hn
  u16*   qB   = (u16*)(act + SA);      // q  (qB,kC,vD contiguous for fused QKV)
  u16*   kC   = (u16*)(act + 2 * SA);  // k
  u16*   vD   = (u16*)(act + 3 * SA);  // v -> ao
  u16*   vTr  = regA;
  u16*   ao   = vD;
  u16*   hn   = regA;
  u16*   h1h  = qB;                    // [R][2048] bf16 half-F activations (spans qB+kC)

  // small scratch in the tail of d_out (overwritten by final FFN2 afterwards)
  float* bqkv  = out + (size_t)out_size - 8192;
  float* qsall = bqkv + 3072;

  transpose_conv3<<<dim3(32, 32, 3), 256, 0, stream>>>(wq, wk, wv_, wqkvT, DD, DD);
  conv_bf16<<<1024, 256, 0, stream>>>(wo, woT);
  transpose_conv<<<dim3(128, 32), 256, 0, stream>>>(w1, w1T, DD, FF);
  transpose_conv<<<dim3(32, 128), 256, 0, stream>>>(w2, w2T, FF, DD);
  prep_kernel<<<3, 1024, 0, stream>>>(bq, bk, bv, pds, bqkv, qsall);

  const int R = G * 1024;

  for (int c0 = 0; c0 < BB / G; c0++) {
    size_t rowoff = (size_t)c0 * R;
    const float* xc = x + rowoff * DD;
    float* outc = out + rowoff * DD;   // fp32 residual stream lives in d_out

    rms_kernel<<<R, 256, 0, stream>>>(xc, rs, regA);

    // fused QKV: N=3072 -> grid (24, R/128); out regions qB/kC/vD via regstride
    mfma_gemm<u16><<<dim3(24, R / 128), 256, 0, stream>>>(
        regA, wqkvT, bqkv, nullptr, qsall, qB,
        DD, DD, DD, 0, 1024, (size_t)R * 1024);

    vtrans_kernel<<<dim3(TT / 64, G * NHEAD), 256, 0, stream>>>(vD, vTr);

    attn_mfma<<<dim3(4, G * NHEAD), 256, 0, stream>>>(
        qB, kC, vTr, pad + rowoff, ao);

    // o-proj: outc = ao @ wo^T + bo + x   (fp32 residual into d_out)
    mfma_gemm<float><<<dim3(8, R / 128), 256, 0, stream>>>(
        ao, woT, bo, xc, nullptr, outc, DD, DD, DD, 0, 1024, 0);

    ln_kernel<<<R, 256, 0, stream>>>(outc, lg, lb, hn);

    // FFN in 2 half-F panels: FFN1 N=2048 (ldc=2048), FFN2 K=2048 RMW residual
    for (int f = 0; f < 2; f++) {
      mfma_gemm<u16><<<dim3(16, R / 128), 256, 0, stream>>>(
          hn, w1T + (size_t)f * 2048 * 1024, b1 + f * 2048, nullptr, nullptr,
          h1h, DD, DD, DD, 1, 2048, 0);
      mfma_gemm<float><<<dim3(8, R / 128), 256, 0, stream>>>(
          h1h, w2T + f * 2048, (f == 0) ? b2 : nullptr, outc, nullptr,
          outc, 2048, FF, 2048, 0, 1024, 0);
    }
  }
}